// Round 1
// baseline (292.493 us; speedup 1.0000x reference)
//
#include <hip/hip_runtime.h>
#include <hip/hip_bf16.h>

typedef unsigned short u16;
typedef __attribute__((ext_vector_type(8))) short bf16x8;
typedef __attribute__((ext_vector_type(4))) float f32x4;

#define T_DIM 2048
#define B_DIM 32
#define H_DIM 512
#define M_DIM (T_DIM * B_DIM)

__device__ inline unsigned pack2(float a, float b) {
  union { __hip_bfloat162 h2; unsigned u; } c;
  c.h2 = __float22bfloat162_rn(make_float2(a, b));
  return c.u;
}

// Precompute: r[b*512+h] = hidden[b]·W1[h] + b_attn[h]; u[h] = W3[h]·W_cov; W2bf = bf16(W2)
__global__ __launch_bounds__(256) void prep_kernel(
    const float* __restrict__ hidden, const float* __restrict__ W_attn,
    const float* __restrict__ b_attn, const float* __restrict__ W_cov,
    u16* __restrict__ W2bf, float* __restrict__ r, float* __restrict__ u)
{
  const int tid = blockIdx.x * 256 + threadIdx.x;  // 0..65535
  const int pair = tid >> 2;                       // b*512 + h
  const int kq = tid & 3;
  const int b = pair >> 9, h = pair & 511;

  // r: 4 threads per (b,h), each sums 128 of K=512
  {
    const float* hid = hidden + b * 512 + kq * 128;
    const float* w1 = W_attn + (size_t)h * 1536 + kq * 128;
    float acc = 0.f;
    #pragma unroll 8
    for (int k = 0; k < 128; k += 4) {
      float4 x = *(const float4*)(hid + k);
      float4 w = *(const float4*)(w1 + k);
      acc += x.x * w.x + x.y * w.y + x.z * w.z + x.w * w.w;
    }
    acc += __shfl_xor(acc, 1);
    acc += __shfl_xor(acc, 2);
    if (kq == 0) r[pair] = acc + b_attn[h];
  }

  // W2 -> bf16: 4 elements per thread (262144 total)
  {
    int j0 = tid * 4;
    int hh = j0 >> 9, kk = j0 & 511;
    float4 w = *(const float4*)(W_attn + (size_t)hh * 1536 + 512 + kk);
    uint2 p;
    p.x = pack2(w.x, w.y);
    p.y = pack2(w.z, w.w);
    *(uint2*)&W2bf[j0] = p;
  }

  // u[h]: first 2048 threads, 4 per h
  if (tid < 2048) {
    int h3 = tid >> 2;
    const float* w3 = W_attn + (size_t)h3 * 1536 + 1024 + kq * 128;
    const float* wc = W_cov + kq * 128;
    float su = 0.f;
    #pragma unroll 8
    for (int k = 0; k < 128; k += 4) {
      float4 a = *(const float4*)(w3 + k);
      float4 c = *(const float4*)(wc + k);
      su += a.x * c.x + a.y * c.y + a.z * c.z + a.w * c.w;
    }
    su += __shfl_xor(su, 1);
    su += __shfl_xor(su, 2);
    if (kq == 0) u[h3] = su;
  }
}

// Main GEMM + fused score reduction.
// A = encoder_outputs [M=65536, K=512] fp32 (row m = t*32+b), Bmat = W2bf [N=512, K=512] bf16.
// e2 = A·B^T; score_partial[m] += sum over this block's 128 h of relu(e2+r+cov*u)*v
__global__ __launch_bounds__(256) void gemm_score(
    const float* __restrict__ enc, const u16* __restrict__ W2bf,
    const float* __restrict__ r, const float* __restrict__ u,
    const float* __restrict__ vv, const float* __restrict__ cov,
    float* __restrict__ part)
{
  const int n0 = blockIdx.x * 128;   // 4 n-tiles (h dim)
  const int m0 = blockIdx.y * 128;   // 512 m-tiles
  const int tid = threadIdx.x;
  const int lane = tid & 63;
  const int wid = tid >> 6;
  const int wm = wid >> 1, wn = wid & 1;
  const int quad = lane >> 4, col = lane & 15;

  __shared__ u16 As[128 * 64];  // [row][k], row stride 64
  __shared__ u16 Bs[128 * 64];  // [h_row][k]

  f32x4 acc[4][4] = {};

  for (int kb = 0; kb < 512; kb += 64) {
    // Stage A tile: 128x64 fp32 -> bf16. 1024 chunks of 8 floats; 4 per thread.
    #pragma unroll
    for (int it = 0; it < 4; ++it) {
      int un = tid + 256 * it;
      int row = un >> 3, ku = (un & 7) * 8;
      const float* ga = enc + (size_t)(m0 + row) * 512 + kb + ku;
      float4 f0 = *(const float4*)ga;
      float4 f1 = *(const float4*)(ga + 4);
      uint4 p;
      p.x = pack2(f0.x, f0.y);
      p.y = pack2(f0.z, f0.w);
      p.z = pack2(f1.x, f1.y);
      p.w = pack2(f1.z, f1.w);
      *(uint4*)&As[row * 64 + ku] = p;
    }
    // Stage B tile: 128x64 bf16 copy. 1024 chunks of 8 bf16 (16B); 4 per thread.
    #pragma unroll
    for (int it = 0; it < 4; ++it) {
      int c = tid + 256 * it;
      int row = c >> 3, kc = (c & 7) * 8;
      *(uint4*)&Bs[row * 64 + kc] =
          *(const uint4*)(W2bf + (size_t)(n0 + row) * 512 + kb + kc);
    }
    __syncthreads();
    #pragma unroll
    for (int ks = 0; ks < 64; ks += 32) {
      bf16x8 af[4], bfr[4];
      #pragma unroll
      for (int i = 0; i < 4; ++i)
        af[i] = *(const bf16x8*)&As[(wm * 64 + i * 16 + col) * 64 + ks + quad * 8];
      #pragma unroll
      for (int j = 0; j < 4; ++j)
        bfr[j] = *(const bf16x8*)&Bs[(wn * 64 + j * 16 + col) * 64 + ks + quad * 8];
      #pragma unroll
      for (int i = 0; i < 4; ++i)
        #pragma unroll
        for (int j = 0; j < 4; ++j)
          acc[i][j] = __builtin_amdgcn_mfma_f32_16x16x32_bf16(af[i], bfr[j], acc[i][j], 0, 0, 0);
    }
    __syncthreads();
  }

  // Epilogue: energy = relu(acc + r[b,h] + cov[b,t]*u[h]); partial score = energy·v over 64 cols/wave
  float uj[4], vj[4];
  #pragma unroll
  for (int j = 0; j < 4; ++j) {
    int gh = n0 + wn * 64 + j * 16 + col;
    uj[j] = u[gh];
    vj[j] = vv[gh];
  }
  #pragma unroll
  for (int i = 0; i < 4; ++i) {
    float sarr[4];
    #pragma unroll
    for (int reg = 0; reg < 4; ++reg) {
      int gm = m0 + wm * 64 + i * 16 + quad * 4 + reg;
      int b = gm & 31, t = gm >> 5;
      float cv = cov[b * 2048 + t];
      const float* rb = r + b * 512;
      float sum = 0.f;
      #pragma unroll
      for (int j = 0; j < 4; ++j) {
        int gh = n0 + wn * 64 + j * 16 + col;
        float e = acc[i][j][reg] + rb[gh] + cv * uj[j];
        e = fmaxf(e, 0.f);
        sum += e * vj[j];
      }
      // reduce over 16 columns (lane bits 0..3)
      sum += __shfl_xor(sum, 1);
      sum += __shfl_xor(sum, 2);
      sum += __shfl_xor(sum, 4);
      sum += __shfl_xor(sum, 8);
      sarr[reg] = sum;
    }
    if (col < 4) {
      float val = (col == 0) ? sarr[0] : (col == 1) ? sarr[1] : (col == 2) ? sarr[2] : sarr[3];
      int gm = m0 + wm * 64 + i * 16 + quad * 4 + col;
      part[(size_t)(blockIdx.x * 2 + wn) * M_DIM + gm] = val;
    }
  }
}

// Softmax over T per batch + coverage update. 32 blocks x 256 threads.
__global__ __launch_bounds__(256) void softmax_kernel(
    const float* __restrict__ part, const float* __restrict__ cov, float* __restrict__ out)
{
  const int b = blockIdx.x;
  const int tid = threadIdx.x;
  const int lane = tid & 63, wid = tid >> 6;
  __shared__ float red[4];
  float loc[8];
  float lmax = -3.4e38f;
  #pragma unroll
  for (int i = 0; i < 8; ++i) {
    int t = tid + i * 256;
    float s = 0.f;
    #pragma unroll
    for (int p = 0; p < 8; ++p) s += part[(size_t)p * M_DIM + t * 32 + b];
    loc[i] = s;
    lmax = fmaxf(lmax, s);
  }
  #pragma unroll
  for (int o = 32; o; o >>= 1) lmax = fmaxf(lmax, __shfl_xor(lmax, o));
  if (lane == 0) red[wid] = lmax;
  __syncthreads();
  float bmax = fmaxf(fmaxf(red[0], red[1]), fmaxf(red[2], red[3]));
  __syncthreads();
  float lsum = 0.f;
  #pragma unroll
  for (int i = 0; i < 8; ++i) { loc[i] = __expf(loc[i] - bmax); lsum += loc[i]; }
  #pragma unroll
  for (int o = 32; o; o >>= 1) lsum += __shfl_xor(lsum, o);
  if (lane == 0) red[wid] = lsum;
  __syncthreads();
  float inv = 1.0f / (red[0] + red[1] + red[2] + red[3]);
  #pragma unroll
  for (int i = 0; i < 8; ++i) {
    int t = tid + i * 256;
    float a = loc[i] * inv;
    out[b * 2048 + t] = a;                               // attn_weights [B,1,T]
    out[65536 + b * 2048 + t] = cov[b * 2048 + t] + a;   // coverage_new [B,T]
  }
}

extern "C" void kernel_launch(void* const* d_in, const int* in_sizes, int n_in,
                              void* d_out, int out_size, void* d_ws, size_t ws_size,
                              hipStream_t stream) {
  const float* hidden = (const float*)d_in[0];   // [1,B,H]
  const float* enc    = (const float*)d_in[1];   // [T,B,H]
  const float* cov    = (const float*)d_in[2];   // [B,T]
  const float* W_attn = (const float*)d_in[3];   // [H,3H]
  const float* b_attn = (const float*)d_in[4];   // [H]
  const float* vv     = (const float*)d_in[5];   // [H]
  const float* W_cov  = (const float*)d_in[6];   // [H,1]
  float* out = (float*)d_out;

  u16* W2bf = (u16*)d_ws;                              // 512 KB
  float* r  = (float*)((char*)d_ws + 512 * 1024);      // 64 KB
  float* u  = r + 32 * 512;                            // 2 KB
  float* part = u + 512;                               // 8 * 65536 * 4 = 2 MB

  hipLaunchKernelGGL(prep_kernel, dim3(256), dim3(256), 0, stream,
                     hidden, W_attn, b_attn, W_cov, W2bf, r, u);
  hipLaunchKernelGGL(gemm_score, dim3(4, 512), dim3(256), 0, stream,
                     enc, W2bf, r, u, vv, cov, part);
  hipLaunchKernelGGL(softmax_kernel, dim3(32), dim3(256), 0, stream,
                     part, cov, out);
}

// Round 2
// 281.737 us; speedup vs baseline: 1.0382x; 1.0382x over previous
//
#include <hip/hip_runtime.h>
#include <hip/hip_bf16.h>

typedef unsigned short u16;
typedef __attribute__((ext_vector_type(8))) short bf16x8;
typedef __attribute__((ext_vector_type(4))) float f32x4;

#define T_DIM 2048
#define B_DIM 32
#define H_DIM 512
#define M_DIM (T_DIM * B_DIM)

__device__ inline unsigned pack2(float a, float b) {
  union { __hip_bfloat162 h2; unsigned u; } c;
  c.h2 = __float22bfloat162_rn(make_float2(a, b));
  return c.u;
}

// Precompute: r[b*512+h] = hidden[b]·W1[h] + b_attn[h]; u[h] = W3[h]·W_cov; W2bf = bf16(W2)
__global__ __launch_bounds__(256) void prep_kernel(
    const float* __restrict__ hidden, const float* __restrict__ W_attn,
    const float* __restrict__ b_attn, const float* __restrict__ W_cov,
    u16* __restrict__ W2bf, float* __restrict__ r, float* __restrict__ u)
{
  const int tid = blockIdx.x * 256 + threadIdx.x;  // 0..65535
  const int pair = tid >> 2;                       // b*512 + h
  const int kq = tid & 3;
  const int b = pair >> 9, h = pair & 511;

  // r: 4 threads per (b,h), each sums 128 of K=512
  {
    const float* hid = hidden + b * 512 + kq * 128;
    const float* w1 = W_attn + (size_t)h * 1536 + kq * 128;
    float acc = 0.f;
    #pragma unroll 8
    for (int k = 0; k < 128; k += 4) {
      float4 x = *(const float4*)(hid + k);
      float4 w = *(const float4*)(w1 + k);
      acc += x.x * w.x + x.y * w.y + x.z * w.z + x.w * w.w;
    }
    acc += __shfl_xor(acc, 1);
    acc += __shfl_xor(acc, 2);
    if (kq == 0) r[pair] = acc + b_attn[h];
  }

  // W2 -> bf16: 4 elements per thread (262144 total)
  {
    int j0 = tid * 4;
    int hh = j0 >> 9, kk = j0 & 511;
    float4 w = *(const float4*)(W_attn + (size_t)hh * 1536 + 512 + kk);
    uint2 p;
    p.x = pack2(w.x, w.y);
    p.y = pack2(w.z, w.w);
    *(uint2*)&W2bf[j0] = p;
  }

  // u[h]: first 2048 threads, 4 per h
  if (tid < 2048) {
    int h3 = tid >> 2;
    const float* w3 = W_attn + (size_t)h3 * 1536 + 1024 + kq * 128;
    const float* wc = W_cov + kq * 128;
    float su = 0.f;
    #pragma unroll 8
    for (int k = 0; k < 128; k += 4) {
      float4 a = *(const float4*)(w3 + k);
      float4 c = *(const float4*)(wc + k);
      su += a.x * c.x + a.y * c.y + a.z * c.z + a.w * c.w;
    }
    su += __shfl_xor(su, 1);
    su += __shfl_xor(su, 2);
    if (kq == 0) u[h3] = su;
  }
}

// One block per 64-row m-tile. A (64x512) staged once into LDS (bf16, XOR-swizzled).
// 4 waves each own a 128-wide n-slab; B fragments straight from global (L2-resident).
// Single barrier; K-loop has no syncs. Epilogue fuses relu + ·v + 16-lane reduce.
__global__ __launch_bounds__(256, 2) void gemm_score(
    const float* __restrict__ enc, const u16* __restrict__ W2bf,
    const float* __restrict__ r, const float* __restrict__ u,
    const float* __restrict__ vv, const float* __restrict__ cov,
    float* __restrict__ part)
{
  const int m0 = blockIdx.x * 64;
  const int tid = threadIdx.x;
  const int lane = tid & 63;
  const int w = tid >> 6;             // wave id -> n-slab [w*128, w*128+128)
  const int quad = lane >> 4, col = lane & 15;

  __shared__ u16 As[64 * 512];        // 64 KB, [row][k] with k-group XOR swizzle

  // ---- Phase 1: stage A fp32 -> bf16, swizzled. Wave reads one row per iter (coalesced 2KB). ----
  #pragma unroll
  for (int it = 0; it < 16; ++it) {
    int un = tid + 256 * it;
    int row = un >> 6;                // 0..63
    int g = un & 63;                  // 16B k-group
    const float* ga = enc + (size_t)(m0 + row) * 512 + g * 8;
    float4 f0 = *(const float4*)ga;
    float4 f1 = *(const float4*)(ga + 4);
    uint4 p;
    p.x = pack2(f0.x, f0.y);
    p.y = pack2(f0.z, f0.w);
    p.z = pack2(f1.x, f1.y);
    p.w = pack2(f1.z, f1.w);
    *(uint4*)&As[row * 512 + (g ^ (row & 7)) * 8] = p;
  }
  __syncthreads();

  // ---- Phase 2: K-loop, no barriers. B frags double-buffered in registers. ----
  f32x4 acc[4][8] = {};
  const u16* bbase = W2bf + (size_t)(w * 128 + col) * 512 + quad * 8;

  bf16x8 bcur[8], bnxt[8];
  #pragma unroll
  for (int j = 0; j < 8; ++j)
    bcur[j] = *(const bf16x8*)(bbase + j * 16 * 512);

  #pragma unroll
  for (int ks = 0; ks < 16; ++ks) {
    if (ks < 15) {
      #pragma unroll
      for (int j = 0; j < 8; ++j)
        bnxt[j] = *(const bf16x8*)(bbase + j * 16 * 512 + (ks + 1) * 32);
    }
    bf16x8 af[4];
    #pragma unroll
    for (int i = 0; i < 4; ++i) {
      int row = i * 16 + col;
      af[i] = *(const bf16x8*)&As[row * 512 + (((ks * 4 + quad) ^ (col & 7))) * 8];
    }
    #pragma unroll
    for (int i = 0; i < 4; ++i)
      #pragma unroll
      for (int j = 0; j < 8; ++j)
        acc[i][j] = __builtin_amdgcn_mfma_f32_16x16x32_bf16(af[i], bcur[j], acc[i][j], 0, 0, 0);
    #pragma unroll
    for (int j = 0; j < 8; ++j) bcur[j] = bnxt[j];
  }

  // ---- Epilogue: e = relu(acc + r[b,h] + cov[b,t]*u[h]); score partial = e·v over this wave's 128 h ----
  float uj[8], vj[8];
  #pragma unroll
  for (int j = 0; j < 8; ++j) {
    int gh = w * 128 + j * 16 + col;
    uj[j] = u[gh];
    vj[j] = vv[gh];
  }
  #pragma unroll
  for (int ih = 0; ih < 2; ++ih) {
    #pragma unroll
    for (int reg = 0; reg < 4; ++reg) {
      int b = (ih * 16 + quad * 4 + reg) & 31;   // m0 % 32 == 0
      const float* rb = r + b * 512;
      float rbj[8];
      #pragma unroll
      for (int j = 0; j < 8; ++j) rbj[j] = rb[w * 128 + j * 16 + col];
      #pragma unroll
      for (int isub = 0; isub < 2; ++isub) {
        int i = ih + isub * 2;
        int m = m0 + i * 16 + quad * 4 + reg;
        int t = m >> 5;
        float cv = cov[b * 2048 + t];
        float s = 0.f;
        #pragma unroll
        for (int j = 0; j < 8; ++j) {
          float e = acc[i][j][reg] + rbj[j] + cv * uj[j];
          e = fmaxf(e, 0.f);
          s += e * vj[j];
        }
        s += __shfl_xor(s, 1);
        s += __shfl_xor(s, 2);
        s += __shfl_xor(s, 4);
        s += __shfl_xor(s, 8);
        if (col == 0) part[(size_t)(w * 32 + b) * 2048 + t] = s;
      }
    }
  }
}

// Softmax over T per batch + coverage update. 32 blocks x 256 threads. part layout [p][b][t] (coalesced).
__global__ __launch_bounds__(256) void softmax_kernel(
    const float* __restrict__ part, const float* __restrict__ cov, float* __restrict__ out)
{
  const int b = blockIdx.x;
  const int tid = threadIdx.x;
  const int lane = tid & 63, wid = tid >> 6;
  __shared__ float red[4];
  float loc[8];
  float lmax = -3.4e38f;
  #pragma unroll
  for (int i = 0; i < 8; ++i) {
    int t = tid + i * 256;
    float s = 0.f;
    #pragma unroll
    for (int p = 0; p < 4; ++p) s += part[(size_t)(p * 32 + b) * 2048 + t];
    loc[i] = s;
    lmax = fmaxf(lmax, s);
  }
  #pragma unroll
  for (int o = 32; o; o >>= 1) lmax = fmaxf(lmax, __shfl_xor(lmax, o));
  if (lane == 0) red[wid] = lmax;
  __syncthreads();
  float bmax = fmaxf(fmaxf(red[0], red[1]), fmaxf(red[2], red[3]));
  __syncthreads();
  float lsum = 0.f;
  #pragma unroll
  for (int i = 0; i < 8; ++i) { loc[i] = __expf(loc[i] - bmax); lsum += loc[i]; }
  #pragma unroll
  for (int o = 32; o; o >>= 1) lsum += __shfl_xor(lsum, o);
  if (lane == 0) red[wid] = lsum;
  __syncthreads();
  float inv = 1.0f / (red[0] + red[1] + red[2] + red[3]);
  #pragma unroll
  for (int i = 0; i < 8; ++i) {
    int t = tid + i * 256;
    float a = loc[i] * inv;
    out[b * 2048 + t] = a;                               // attn_weights [B,1,T]
    out[65536 + b * 2048 + t] = cov[b * 2048 + t] + a;   // coverage_new [B,T]
  }
}

extern "C" void kernel_launch(void* const* d_in, const int* in_sizes, int n_in,
                              void* d_out, int out_size, void* d_ws, size_t ws_size,
                              hipStream_t stream) {
  const float* hidden = (const float*)d_in[0];   // [1,B,H]
  const float* enc    = (const float*)d_in[1];   // [T,B,H]
  const float* cov    = (const float*)d_in[2];   // [B,T]
  const float* W_attn = (const float*)d_in[3];   // [H,3H]
  const float* b_attn = (const float*)d_in[4];   // [H]
  const float* vv     = (const float*)d_in[5];   // [H]
  const float* W_cov  = (const float*)d_in[6];   // [H,1]
  float* out = (float*)d_out;

  u16* W2bf = (u16*)d_ws;                              // 512 KB
  float* r  = (float*)((char*)d_ws + 512 * 1024);      // 64 KB
  float* u  = r + 32 * 512;                            // 2 KB
  float* part = u + 512;                               // 4 * 65536 * 4 = 1 MB

  hipLaunchKernelGGL(prep_kernel, dim3(256), dim3(256), 0, stream,
                     hidden, W_attn, b_attn, W_cov, W2bf, r, u);
  hipLaunchKernelGGL(gemm_score, dim3(1024), dim3(256), 0, stream,
                     enc, W2bf, r, u, vv, cov, part);
  hipLaunchKernelGGL(softmax_kernel, dim3(32), dim3(256), 0, stream,
                     part, cov, out);
}

// Round 3
// 273.225 us; speedup vs baseline: 1.0705x; 1.0312x over previous
//
#include <hip/hip_runtime.h>
#include <hip/hip_bf16.h>

typedef unsigned short u16;
typedef __attribute__((ext_vector_type(8))) short bf16x8;
typedef __attribute__((ext_vector_type(4))) float f32x4;

#define T_DIM 2048
#define B_DIM 32
#define H_DIM 512
#define M_DIM (T_DIM * B_DIM)

__device__ inline unsigned pack2(float a, float b) {
  union { __hip_bfloat162 h2; unsigned u; } c;
  c.h2 = __float22bfloat162_rn(make_float2(a, b));
  return c.u;
}

// Precompute: r[b*512+h] = hidden[b]·W1[h] + b_attn[h]; u[h] = W3[h]·W_cov;
// W2bf = bf16(W2) in FRAGMENT-MAJOR layout: chunk (f= h>>4, ks= k>>5) of 1KB,
// within chunk: lane (quad= (k>>3)&3, c= h&15) * 16B + (k&7)*2B.
// A wave's MFMA B-fragment load == one contiguous 1KB chunk at base+lane*16.
__global__ __launch_bounds__(256) void prep_kernel(
    const float* __restrict__ hidden, const float* __restrict__ W_attn,
    const float* __restrict__ b_attn, const float* __restrict__ W_cov,
    u16* __restrict__ W2bf, float* __restrict__ r, float* __restrict__ u)
{
  const int tid = blockIdx.x * 256 + threadIdx.x;  // 0..65535
  const int pair = tid >> 2;                       // b*512 + h
  const int kq = tid & 3;
  const int b = pair >> 9, h = pair & 511;

  // r: 4 threads per (b,h), each sums 128 of K=512
  {
    const float* hid = hidden + b * 512 + kq * 128;
    const float* w1 = W_attn + (size_t)h * 1536 + kq * 128;
    float acc = 0.f;
    #pragma unroll 8
    for (int k = 0; k < 128; k += 4) {
      float4 x = *(const float4*)(hid + k);
      float4 w = *(const float4*)(w1 + k);
      acc += x.x * w.x + x.y * w.y + x.z * w.z + x.w * w.w;
    }
    acc += __shfl_xor(acc, 1);
    acc += __shfl_xor(acc, 2);
    if (kq == 0) r[pair] = acc + b_attn[h];
  }

  // W2 -> bf16 fragment-major: 4 consecutive k per thread
  {
    int j0 = tid * 4;
    int hh = j0 >> 9, kk = j0 & 511;
    float4 w = *(const float4*)(W_attn + (size_t)hh * 1536 + 512 + kk);
    uint2 p;
    p.x = pack2(w.x, w.y);
    p.y = pack2(w.z, w.w);
    int f = hh >> 4, c = hh & 15;
    int ks = kk >> 5, quad = (kk >> 3) & 3, e = kk & 7;   // e in {0,4}
    *(uint2*)(W2bf + (size_t)((f * 16 + ks) * 64 + quad * 16 + c) * 8 + e) = p;
  }

  // u[h]: first 2048 threads, 4 per h
  if (tid < 2048) {
    int h3 = tid >> 2;
    const float* w3 = W_attn + (size_t)h3 * 1536 + 1024 + kq * 128;
    const float* wc = W_cov + kq * 128;
    float su = 0.f;
    #pragma unroll 8
    for (int k = 0; k < 128; k += 4) {
      float4 a = *(const float4*)(w3 + k);
      float4 c = *(const float4*)(wc + k);
      su += a.x * c.x + a.y * c.y + a.z * c.z + a.w * c.w;
    }
    su += __shfl_xor(su, 1);
    su += __shfl_xor(su, 2);
    if (kq == 0) u[h3] = su;
  }
}

// One block (512 thr, 8 waves) per 64-row m-tile. A (64x512) staged once into LDS
// (bf16, XOR-swizzled), single barrier. Each wave owns a 64-wide n-slab (8*64=512=N);
// B fragments are coalesced 1KB loads from the fragment-major W2bf (L2-resident),
// register double-buffered. K-loop has no syncs.
__global__ __launch_bounds__(512, 4) void gemm_score(
    const float* __restrict__ enc, const u16* __restrict__ W2bf,
    const float* __restrict__ r, const float* __restrict__ u,
    const float* __restrict__ vv, const float* __restrict__ cov,
    float* __restrict__ part)
{
  const int m0 = blockIdx.x * 64;
  const int tid = threadIdx.x;
  const int lane = tid & 63;
  const int w = tid >> 6;             // wave id 0..7 -> n-slab [w*64, w*64+64)
  const int quad = lane >> 4, col = lane & 15;

  __shared__ u16 As[64 * 512];        // 64 KB, [row][k] with 16B-group XOR swizzle

  // ---- Phase 1: stage A fp32 -> bf16, swizzled. 64 rows x 64 groups / 512 thr = 8 iters ----
  #pragma unroll
  for (int it = 0; it < 8; ++it) {
    int un = tid + 512 * it;
    int row = un >> 6;                // 0..63
    int g = un & 63;                  // 16B k-group
    const float* ga = enc + (size_t)(m0 + row) * 512 + g * 8;
    float4 f0 = *(const float4*)ga;
    float4 f1 = *(const float4*)(ga + 4);
    uint4 p;
    p.x = pack2(f0.x, f0.y);
    p.y = pack2(f0.z, f0.w);
    p.z = pack2(f1.x, f1.y);
    p.w = pack2(f1.z, f1.w);
    *(uint4*)&As[row * 512 + (g ^ (row & 7)) * 8] = p;
  }
  __syncthreads();

  // ---- Phase 2: K-loop, no barriers. B frags: coalesced 1KB loads, double-buffered. ----
  f32x4 acc[4][4] = {};
  const u16* bbase = W2bf + (size_t)w * 32768 + lane * 8;  // f-base = w*4; chunk=512 u16

  bf16x8 bcur[4], bnxt[4];
  #pragma unroll
  for (int j = 0; j < 4; ++j)
    bcur[j] = *(const bf16x8*)(bbase + j * 8192);

  #pragma unroll
  for (int ks = 0; ks < 16; ++ks) {
    if (ks < 15) {
      #pragma unroll
      for (int j = 0; j < 4; ++j)
        bnxt[j] = *(const bf16x8*)(bbase + j * 8192 + (ks + 1) * 512);
    }
    bf16x8 af[4];
    #pragma unroll
    for (int i = 0; i < 4; ++i) {
      int row = i * 16 + col;
      af[i] = *(const bf16x8*)&As[row * 512 + ((ks * 4 + quad) ^ (col & 7)) * 8];
    }
    #pragma unroll
    for (int i = 0; i < 4; ++i)
      #pragma unroll
      for (int j = 0; j < 4; ++j)
        acc[i][j] = __builtin_amdgcn_mfma_f32_16x16x32_bf16(af[i], bcur[j], acc[i][j], 0, 0, 0);
    #pragma unroll
    for (int j = 0; j < 4; ++j) bcur[j] = bnxt[j];
  }

  // ---- Epilogue: e = relu(acc + r[b,h] + cov[b,t]*u[h]); partial = e·v over wave's 64 h ----
  float uj[4], vj[4];
  #pragma unroll
  for (int j = 0; j < 4; ++j) {
    int gh = w * 64 + j * 16 + col;
    uj[j] = u[gh];
    vj[j] = vv[gh];
  }
  #pragma unroll
  for (int pair = 0; pair < 2; ++pair) {
    #pragma unroll
    for (int reg = 0; reg < 4; ++reg) {
      int b = pair * 16 + quad * 4 + reg;       // = m & 31 (m0 % 64 == 0)
      const float* rb = r + b * 512;
      float rbj[4];
      #pragma unroll
      for (int j = 0; j < 4; ++j) rbj[j] = rb[w * 64 + j * 16 + col];
      #pragma unroll
      for (int isub = 0; isub < 2; ++isub) {
        int i = pair + isub * 2;
        int t = (m0 >> 5) + isub;               // m = m0 + i*16 + quad*4 + reg; t = m>>5
        float cv = cov[b * 2048 + t];
        float s = 0.f;
        #pragma unroll
        for (int j = 0; j < 4; ++j) {
          float e = acc[i][j][reg] + rbj[j] + cv * uj[j];
          e = fmaxf(e, 0.f);
          s += e * vj[j];
        }
        s += __shfl_xor(s, 1);
        s += __shfl_xor(s, 2);
        s += __shfl_xor(s, 4);
        s += __shfl_xor(s, 8);
        if (col == 0) part[(size_t)(w * 32 + b) * 2048 + t] = s;
      }
    }
  }
}

// Softmax over T per batch + coverage update. 32 blocks x 256 threads. part layout [p][b][t].
__global__ __launch_bounds__(256) void softmax_kernel(
    const float* __restrict__ part, const float* __restrict__ cov, float* __restrict__ out)
{
  const int b = blockIdx.x;
  const int tid = threadIdx.x;
  const int lane = tid & 63, wid = tid >> 6;
  __shared__ float red[4];
  float loc[8];
  float lmax = -3.4e38f;
  #pragma unroll
  for (int i = 0; i < 8; ++i) {
    int t = tid + i * 256;
    float s = 0.f;
    #pragma unroll
    for (int p = 0; p < 8; ++p) s += part[(size_t)(p * 32 + b) * 2048 + t];
    loc[i] = s;
    lmax = fmaxf(lmax, s);
  }
  #pragma unroll
  for (int o = 32; o; o >>= 1) lmax = fmaxf(lmax, __shfl_xor(lmax, o));
  if (lane == 0) red[wid] = lmax;
  __syncthreads();
  float bmax = fmaxf(fmaxf(red[0], red[1]), fmaxf(red[2], red[3]));
  __syncthreads();
  float lsum = 0.f;
  #pragma unroll
  for (int i = 0; i < 8; ++i) { loc[i] = __expf(loc[i] - bmax); lsum += loc[i]; }
  #pragma unroll
  for (int o = 32; o; o >>= 1) lsum += __shfl_xor(lsum, o);
  if (lane == 0) red[wid] = lsum;
  __syncthreads();
  float inv = 1.0f / (red[0] + red[1] + red[2] + red[3]);
  #pragma unroll
  for (int i = 0; i < 8; ++i) {
    int t = tid + i * 256;
    float a = loc[i] * inv;
    out[b * 2048 + t] = a;                               // attn_weights [B,1,T]
    out[65536 + b * 2048 + t] = cov[b * 2048 + t] + a;   // coverage_new [B,T]
  }
}

extern "C" void kernel_launch(void* const* d_in, const int* in_sizes, int n_in,
                              void* d_out, int out_size, void* d_ws, size_t ws_size,
                              hipStream_t stream) {
  const float* hidden = (const float*)d_in[0];   // [1,B,H]
  const float* enc    = (const float*)d_in[1];   // [T,B,H]
  const float* cov    = (const float*)d_in[2];   // [B,T]
  const float* W_attn = (const float*)d_in[3];   // [H,3H]
  const float* b_attn = (const float*)d_in[4];   // [H]
  const float* vv     = (const float*)d_in[5];   // [H]
  const float* W_cov  = (const float*)d_in[6];   // [H,1]
  float* out = (float*)d_out;

  u16* W2bf = (u16*)d_ws;                              // 512 KB (fragment-major)
  float* r  = (float*)((char*)d_ws + 512 * 1024);      // 64 KB
  float* u  = r + 32 * 512;                            // 2 KB
  float* part = u + 512;                               // 8 * 65536 * 4 = 2 MB

  hipLaunchKernelGGL(prep_kernel, dim3(256), dim3(256), 0, stream,
                     hidden, W_attn, b_attn, W_cov, W2bf, r, u);
  hipLaunchKernelGGL(gemm_score, dim3(1024), dim3(512), 0, stream,
                     enc, W2bf, r, u, vv, cov, part);
  hipLaunchKernelGGL(softmax_kernel, dim3(32), dim3(256), 0, stream,
                     part, cov, out);
}